// Round 3
// baseline (215.596 us; speedup 1.0000x reference)
//
#include <hip/hip_runtime.h>
#include <hip/hip_bf16.h>

#define B_  256
#define H_  1024
#define D_  256
#define G_  32
#define C_  16
#define O_  256
#define HD_ 1280          // H + D
#define N1_ 16384         // C*H
#define RS_ 40            // LDS row stride in shorts (80 B): 16B-aligned b128
                          // rows; fragment reads touch all 32 banks uniformly

typedef __attribute__((ext_vector_type(8)))  short short8;
typedef __attribute__((ext_vector_type(4)))  short s16x4;
typedef __attribute__((ext_vector_type(4)))  float f32x4;
typedef __attribute__((ext_vector_type(16))) float f32x16;

#define MFMA32(a, b, c) __builtin_amdgcn_mfma_f32_32x32x16_bf16((a), (b), (c), 0, 0, 0)

// tanh via fast exp + hw rcp; clamped to +-(1-6e-8) so that the downstream
// blend denominator 1 + tA*tB is always > 0 (never 0*inf = NaN).
__device__ __forceinline__ float tanh_c(float x) {
    float y = __expf(2.f * x);
    float t = 1.f - 2.f * __builtin_amdgcn_rcpf(y + 1.f);
    return fminf(fmaxf(t, -0.99999994f), 0.99999994f);
}

// Split fp32 into bf16 hi + bf16 lo (both truncated).
__device__ __forceinline__ short bfhi(float x) {
    return (short)(__float_as_uint(x) >> 16);
}
__device__ __forceinline__ short bflo(float x) {
    float fhi = __uint_as_float(__float_as_uint(x) & 0xFFFF0000u);
    return (short)(__float_as_uint(x - fhi) >> 16);
}

__device__ __forceinline__ void split4(const float4 v, s16x4& hi, s16x4& lo) {
    hi[0] = bfhi(v.x); lo[0] = bflo(v.x);
    hi[1] = bfhi(v.y); lo[1] = bflo(v.y);
    hi[2] = bfhi(v.z); lo[2] = bflo(v.z);
    hi[3] = bfhi(v.w); lo[3] = bflo(v.w);
}

// ---------------------------------------------------------------------------
// Kernel 1: tA[b, c*H+o] = tanh( sum_h hidden[b,h]*attn_w[c,o,h] + attn_b[c,o] )
// GEMM M=256, N=16384, K=1024.  BM=128 x BN=64, 256 thr (4 waves of 64x32 via
// 2x 32x32x16 MFMA), grid (2,256).
// Round-3 structure: SINGLE-buffered LDS (30.7 KB) + __launch_bounds__(256,4)
// => 4 co-resident blocks/CU (16 waves) — TLP hides the per-slab vmcnt/barrier
// stalls that round-2's 2-block residency exposed.  1-deep register prefetch;
// raw s_barrier with lgkmcnt(0)-only fences (global loads never drained by a
// vmcnt(0)).  A comes pre-split (bf16 hi/lo planes) from gemm2's prepass.
// ---------------------------------------------------------------------------
__global__ __launch_bounds__(256, 4) void gemm1_kernel(
    const short* __restrict__ hidH, const short* __restrict__ hidL,
    const float* __restrict__ attn_w, const float* __restrict__ attn_b,
    float* __restrict__ hp)
{
    __shared__ short AsH[128 * RS_];
    __shared__ short AsL[128 * RS_];
    __shared__ short BsH[64 * RS_];
    __shared__ short BsL[64 * RS_];

    const int tid  = threadIdx.x;
    const int wave = tid >> 6, lane = tid & 63;
    const int m0 = blockIdx.x * 128;   // 2 m-tiles (LLC absorbs the 2x attn_w)
    const int n0 = blockIdx.y * 64;
    const int wm = (wave >> 1) * 64;   // wave tile 64(m) x 32(n)
    const int wn = (wave & 1) * 32;
    const int l31 = lane & 31;
    const int kh  = (lane >> 5) * 8;   // k-half offset (shorts) for 32x32x16

    f32x16 acc0, acc1;
    #pragma unroll
    for (int i = 0; i < 16; ++i) { acc0[i] = 0.f; acc1[i] = 0.f; }

    // Staging: A-tile 128x32 shorts/plane = 512 short8 chunks (2/thread/plane);
    // B-tile 64x32 floats = 512 float4 chunks (2/thread).
    const int rA = tid >> 2, cA = (tid & 3) * 8;
    const int rB = tid >> 3, cB = (tid & 7) * 4;
    const short* pAH0 = hidH + (size_t)(m0 + rA) * H_ + cA;
    const short* pAH1 = pAH0 + 64 * H_;
    const short* pAL0 = hidL + (size_t)(m0 + rA) * H_ + cA;
    const short* pAL1 = pAL0 + 64 * H_;
    const float* pB0  = attn_w + (size_t)(n0 + rB) * HD_ + cB;
    const float* pB1  = pB0 + (size_t)32 * HD_;

    const int wA0 = rA * RS_ + cA, wA1 = wA0 + 64 * RS_;
    const int wB0 = rB * RS_ + cB, wB1 = wB0 + 32 * RS_;
    const int aoff0 = (wm + l31) * RS_ + kh;
    const int aoff1 = aoff0 + 32 * RS_;
    const int boff  = (wn + l31) * RS_ + kh;

    short8 rH0, rH1, rL0, rL1;
    float4 rb0, rb1;

#define STAGE_WRITE()                                                         \
    {                                                                         \
        *(short8*)(&AsH[wA0]) = rH0;                                          \
        *(short8*)(&AsH[wA1]) = rH1;                                          \
        *(short8*)(&AsL[wA0]) = rL0;                                          \
        *(short8*)(&AsL[wA1]) = rL1;                                          \
        s16x4 h_, l_;                                                         \
        split4(rb0, h_, l_);                                                  \
        *(s16x4*)(&BsH[wB0]) = h_;                                            \
        *(s16x4*)(&BsL[wB0]) = l_;                                            \
        split4(rb1, h_, l_);                                                  \
        *(s16x4*)(&BsH[wB1]) = h_;                                            \
        *(s16x4*)(&BsL[wB1]) = l_;                                            \
    }

#define STAGE_LOAD(KOFF)                                                      \
    {                                                                         \
        rH0 = *(const short8*)(pAH0 + (KOFF));                                \
        rH1 = *(const short8*)(pAH1 + (KOFF));                                \
        rL0 = *(const short8*)(pAL0 + (KOFF));                                \
        rL1 = *(const short8*)(pAL1 + (KOFF));                                \
        rb0 = *(const float4*)(pB0 + (KOFF));                                 \
        rb1 = *(const float4*)(pB1 + (KOFF));                                 \
    }

    // prologue: slab0 -> regs -> LDS; slab1 -> regs; fence+barrier
    STAGE_LOAD(0)
    STAGE_WRITE()
    STAGE_LOAD(32)
    asm volatile("s_waitcnt lgkmcnt(0)" ::: "memory");
    __builtin_amdgcn_s_barrier();

    for (int k = 0; k < 32; ++k) {
        // compute slab k from LDS
        #pragma unroll
        for (int ks = 0; ks < 2; ++ks) {
            short8 ah0 = *(const short8*)(&AsH[aoff0 + ks * 16]);
            short8 ah1 = *(const short8*)(&AsH[aoff1 + ks * 16]);
            short8 al0 = *(const short8*)(&AsL[aoff0 + ks * 16]);
            short8 al1 = *(const short8*)(&AsL[aoff1 + ks * 16]);
            short8 bh  = *(const short8*)(&BsH[boff + ks * 16]);
            short8 bl  = *(const short8*)(&BsL[boff + ks * 16]);
            acc0 = MFMA32(ah0, bh, acc0);
            acc1 = MFMA32(ah1, bh, acc1);
            acc0 = MFMA32(al0, bh, acc0);
            acc1 = MFMA32(al1, bh, acc1);
            acc0 = MFMA32(ah0, bl, acc0);
            acc1 = MFMA32(ah1, bl, acc1);
        }
        if (k < 31) {
            // all waves' ds_reads of this slab complete before overwrite
            asm volatile("s_waitcnt lgkmcnt(0)" ::: "memory");
            __builtin_amdgcn_s_barrier();
            STAGE_WRITE()                       // slab k+1 (vmcnt wait implicit)
            if (k < 30) STAGE_LOAD((k + 2) * 32)  // issue slab k+2
            asm volatile("s_waitcnt lgkmcnt(0)" ::: "memory");
            __builtin_amdgcn_s_barrier();
        }
    }
#undef STAGE_WRITE
#undef STAGE_LOAD

    // 32x32 C/D layout: col = lane&31, row = (r&3) + 8*(r>>2) + 4*(lane>>5).
    const int col  = n0 + wn + l31;
    const float bias = attn_b[col];
    const int rbase = m0 + wm + (lane >> 5) * 4;
    float* dcol = hp + col;
    #pragma unroll
    for (int r = 0; r < 16; ++r) {
        const int row = rbase + (r & 3) + 8 * (r >> 2);
        dcol[(size_t)row * N1_]        = tanh_c(acc0[r] + bias);
        dcol[(size_t)(row + 32) * N1_] = tanh_c(acc1[r] + bias);
    }
}

// ---------------------------------------------------------------------------
// Kernel 2: tB[c,g,o] = tanh( sum_d enc[c,g,d] * attn_w[c,o,H+d] )
// Per-c GEMM M=32, N=1024, K=256; grid (16,16)=256 blocks.
// Prepass folded in: split hidden (B,H) into bf16 hi/lo planes for gemm1.
// ---------------------------------------------------------------------------
__global__ __launch_bounds__(256) void gemm2_kernel(
    const float* __restrict__ enc, const float* __restrict__ attn_w,
    const float* __restrict__ hidden, float* __restrict__ ep,
    short* __restrict__ hidH, short* __restrict__ hidL)
{
    const int tid  = threadIdx.x;
    const int wave = tid >> 6, lane = tid & 63;

    {   // hidden -> bf16 hi/lo planes (256 blocks x 1024 elems = B_*H_)
        const int base = (blockIdx.y * 16 + blockIdx.x) * 1024 + tid * 4;
        const float4 h4 = *(const float4*)(hidden + base);
        s16x4 hh, ll;
        split4(h4, hh, ll);
        *(s16x4*)(hidH + base) = hh;
        *(s16x4*)(hidL + base) = ll;
    }

    const int c  = blockIdx.y;
    const int n0 = blockIdx.x * 64 + wave * 16;   // o tile, 16 per wave
    const int l16 = lane & 15;
    const int lk  = (lane >> 4) * 8;

#define MFMA16(a, b, c) __builtin_amdgcn_mfma_f32_16x16x32_bf16((a), (b), (c), 0, 0, 0)
    f32x4 acc[2];
    acc[0] = f32x4{0.f, 0.f, 0.f, 0.f};
    acc[1] = f32x4{0.f, 0.f, 0.f, 0.f};

    const float* encp = enc + c * (G_ * D_);
    const float* wp   = attn_w + (size_t)c * H_ * HD_ + H_;

    #pragma unroll
    for (int kk = 0; kk < 8; ++kk) {
        const int k0 = kk * 32 + lk;
        short8 ah[2], al[2], bh, bl;
        #pragma unroll
        for (int mi = 0; mi < 2; ++mi) {
            const float* p = encp + (mi * 16 + l16) * D_ + k0;
            s16x4 h0, l0, h1, l1;
            split4(*(const float4*)p, h0, l0);
            split4(*(const float4*)(p + 4), h1, l1);
            ah[mi] = short8{h0[0],h0[1],h0[2],h0[3],h1[0],h1[1],h1[2],h1[3]};
            al[mi] = short8{l0[0],l0[1],l0[2],l0[3],l1[0],l1[1],l1[2],l1[3]};
        }
        {
            const float* p = wp + (size_t)(n0 + l16) * HD_ + k0;
            s16x4 h0, l0, h1, l1;
            split4(*(const float4*)p, h0, l0);
            split4(*(const float4*)(p + 4), h1, l1);
            bh = short8{h0[0],h0[1],h0[2],h0[3],h1[0],h1[1],h1[2],h1[3]};
            bl = short8{l0[0],l0[1],l0[2],l0[3],l1[0],l1[1],l1[2],l1[3]};
        }
        #pragma unroll
        for (int mi = 0; mi < 2; ++mi) {
            acc[mi] = MFMA16(ah[mi], bh, acc[mi]);
            acc[mi] = MFMA16(al[mi], bh, acc[mi]);
            acc[mi] = MFMA16(ah[mi], bl, acc[mi]);
        }
    }

    const int lr = (lane >> 4) * 4;
    #pragma unroll
    for (int mi = 0; mi < 2; ++mi) {
        const int g = mi * 16 + lr;
        const int o = n0 + l16;
        float* dst = ep + (c * G_ + g) * H_ + o;
        f32x4 vacc = acc[mi];
        dst[0]      = tanh_c(vacc[0]);
        dst[H_]     = tanh_c(vacc[1]);
        dst[2 * H_] = tanh_c(vacc[2]);
        dst[3 * H_] = tanh_c(vacc[3]);
    }
#undef MFMA16
}

// ---------------------------------------------------------------------------
// Kernel 3: per (c, 4 b's): scores[g] = sum_h blend(tA,tB)*v where
// blend = (tA+tB)/(1+tA*tB) = tanh(A+B) exactly; softmax over g; att_cat out;
// weighted[b,c,d] = sum_g att*enc.
// ---------------------------------------------------------------------------
__global__ __launch_bounds__(256) void attn_kernel(
    const float* __restrict__ hp, const float* __restrict__ ep,
    const float* __restrict__ v, const float* __restrict__ enc,
    float* __restrict__ out, float* __restrict__ wt)
{
    const int c  = blockIdx.x;
    const int b0 = blockIdx.y * 4;
    const int tid  = threadIdx.x;
    const int wave = tid >> 6, lane = tid & 63;

    __shared__ float s_att[4][G_];
    __shared__ float s_sc[4][G_];

    // h index mapping: h = lane*4 + j*256 + e  (same partition for hp/ep/v)
    f32x4 vv[4], tav[4][4];
    const float* vrow = v + c * H_;
    #pragma unroll
    for (int j = 0; j < 4; ++j)
        vv[j] = *(const f32x4*)(vrow + lane * 4 + j * 256);
    #pragma unroll
    for (int bi = 0; bi < 4; ++bi) {
        const float* hprow = hp + (size_t)(b0 + bi) * N1_ + c * H_;
        #pragma unroll
        for (int j = 0; j < 4; ++j)
            tav[bi][j] = *(const f32x4*)(hprow + lane * 4 + j * 256);
    }

    #pragma unroll
    for (int gg = 0; gg < 8; ++gg) {
        const int g = wave * 8 + gg;
        const float* eprow = ep + (size_t)(c * G_ + g) * H_;
        float s[4] = {0.f, 0.f, 0.f, 0.f};
        #pragma unroll
        for (int j = 0; j < 4; ++j) {
            const f32x4 tb = *(const f32x4*)(eprow + lane * 4 + j * 256);
            #pragma unroll
            for (int e = 0; e < 4; ++e) {
                const float tbx = tb[e];
                const float w   = vv[j][e];
                #pragma unroll
                for (int bi = 0; bi < 4; ++bi) {
                    const float ta  = tav[bi][j][e];
                    const float num = ta + tbx;
                    const float den = fmaf(ta, tbx, 1.f);
                    s[bi] = fmaf(num * __builtin_amdgcn_rcpf(den), w, s[bi]);
                }
            }
        }
        #pragma unroll
        for (int off = 32; off > 0; off >>= 1) {
            s[0] += __shfl_down(s[0], off, 64);
            s[1] += __shfl_down(s[1], off, 64);
            s[2] += __shfl_down(s[2], off, 64);
            s[3] += __shfl_down(s[3], off, 64);
        }
        if (lane == 0) {
            s_sc[0][g] = s[0]; s_sc[1][g] = s[1];
            s_sc[2][g] = s[2]; s_sc[3][g] = s[3];
        }
    }
    __syncthreads();

    if (tid < 128) {
        const int bi = tid >> 5, g = tid & 31;
        float sv = s_sc[bi][g];
        float m = sv;
        #pragma unroll
        for (int off = 16; off > 0; off >>= 1)
            m = fmaxf(m, __shfl_xor(m, off, 32));
        const float e = __expf(sv - m);
        float sum = e;
        #pragma unroll
        for (int off = 16; off > 0; off >>= 1)
            sum += __shfl_xor(sum, off, 32);
        const float a = e / sum;
        s_att[bi][g] = a;
        out[(size_t)(b0 + bi) * (C_ * G_) + c * G_ + g] = a;   // att_cat
    }
    __syncthreads();

    // weighted[b,c,d], thread = d; enc element shared across the 4 b's
    float w0 = 0.f, w1 = 0.f, w2 = 0.f, w3 = 0.f;
    const float* encc = enc + c * (G_ * D_) + tid;
    #pragma unroll
    for (int g = 0; g < G_; ++g) {
        const float e = encc[g * D_];
        w0 = fmaf(s_att[0][g], e, w0);
        w1 = fmaf(s_att[1][g], e, w1);
        w2 = fmaf(s_att[2][g], e, w2);
        w3 = fmaf(s_att[3][g], e, w3);
    }
    wt[(size_t)((b0 + 0) * C_ + c) * D_ + tid] = w0;
    wt[(size_t)((b0 + 1) * C_ + c) * D_ + tid] = w1;
    wt[(size_t)((b0 + 2) * C_ + c) * D_ + tid] = w2;
    wt[(size_t)((b0 + 3) * C_ + c) * D_ + tid] = w3;
}

// ---------------------------------------------------------------------------
// Kernel 4: pooled[b,d] = mean_c weighted; out[b,o] = pooled.out_w[o,:] + out_b
// ---------------------------------------------------------------------------
__global__ __launch_bounds__(256) void out_kernel(
    const float* __restrict__ wt, const float* __restrict__ out_w,
    const float* __restrict__ out_b, float* __restrict__ out)
{
    const int b = blockIdx.x, tid = threadIdx.x;
    __shared__ float pooled[D_];

    float s = 0.f;
    #pragma unroll
    for (int c = 0; c < C_; ++c)
        s += wt[(size_t)(b * C_ + c) * D_ + tid];
    pooled[tid] = s * (1.f / 16.f);
    __syncthreads();

    float acc = out_b[tid];
    const float* wrow = out_w + tid * D_;
    #pragma unroll 8
    for (int dc = 0; dc < 64; ++dc) {
        float4 w4 = *(const float4*)(wrow + dc * 4);
        acc += pooled[dc * 4 + 0] * w4.x;
        acc += pooled[dc * 4 + 1] * w4.y;
        acc += pooled[dc * 4 + 2] * w4.z;
        acc += pooled[dc * 4 + 3] * w4.w;
    }
    out[(size_t)B_ * (C_ * G_) + b * O_ + tid] = acc;
}

extern "C" void kernel_launch(void* const* d_in, const int* in_sizes, int n_in,
                              void* d_out, int out_size, void* d_ws, size_t ws_size,
                              hipStream_t stream) {
    const float* hidden = (const float*)d_in[0];   // (B,H)     fp32
    const float* enc    = (const float*)d_in[1];   // (C,G,D)   fp32
    const float* attn_w = (const float*)d_in[2];   // (C,H,H+D) fp32
    const float* attn_b = (const float*)d_in[3];   // (C,H)     fp32
    const float* v      = (const float*)d_in[4];   // (C,H)     fp32
    const float* out_w  = (const float*)d_in[5];   // (O,D)     fp32
    const float* out_b  = (const float*)d_in[6];   // (O,)      fp32
    float* out = (float*)d_out;                    // att_cat (B,C*G) ++ out (B,O)

    float* hp = (float*)d_ws;                      // (B, C*H)  tA fp32: 16.78 MB
    float* ep = hp + (size_t)B_ * N1_;             // (C, G, H) tB fp32:  2.10 MB
    float* wt = ep + (size_t)C_ * G_ * H_;         // (B, C, D) fp32:     4.19 MB
    short* hidH = (short*)(wt + (size_t)B_ * C_ * D_);  // (B,H) bf16 hi: 512 KB
    short* hidL = hidH + (size_t)B_ * H_;               // (B,H) bf16 lo: 512 KB

    // gemm2 first: it also produces the hidden bf16 hi/lo planes gemm1 reads.
    gemm2_kernel<<<dim3(16, C_), 256, 0, stream>>>(enc, attn_w, hidden, ep, hidH, hidL);
    gemm1_kernel<<<dim3(2, 256), 256, 0, stream>>>(hidH, hidL, attn_w, attn_b, hp);
    attn_kernel<<<dim3(C_, B_ / 4), 256, 0, stream>>>(hp, ep, v, enc, out, wt);
    out_kernel<<<B_, 256, 0, stream>>>(wt, out_w, out_b, out);
}

// Round 4
// 205.401 us; speedup vs baseline: 1.0496x; 1.0496x over previous
//
#include <hip/hip_runtime.h>
#include <hip/hip_bf16.h>

#define B_  256
#define H_  1024
#define D_  256
#define G_  32
#define C_  16
#define O_  256
#define HD_ 1280          // H + D
#define N1_ 16384         // C*H
#define RS_ 40            // LDS row stride in shorts (80 B): 16B-aligned b128

typedef __attribute__((ext_vector_type(8)))  short short8;
typedef __attribute__((ext_vector_type(4)))  short s16x4;
typedef __attribute__((ext_vector_type(4)))  float f32x4;
typedef __attribute__((ext_vector_type(16))) float f32x16;

#define MFMA32(a, b, c) __builtin_amdgcn_mfma_f32_32x32x16_bf16((a), (b), (c), 0, 0, 0)

// tanh via fast exp + hw rcp; clamped to +-(1-6e-8) so that the downstream
// blend denominator 1 + tA*tB is always > 0 (never 0*inf = NaN).
__device__ __forceinline__ float tanh_c(float x) {
    float y = __expf(2.f * x);
    float t = 1.f - 2.f * __builtin_amdgcn_rcpf(y + 1.f);
    return fminf(fmaxf(t, -0.99999994f), 0.99999994f);
}

// Split fp32 into bf16 hi + bf16 lo (both truncated).
__device__ __forceinline__ short bfhi(float x) {
    return (short)(__float_as_uint(x) >> 16);
}
__device__ __forceinline__ short bflo(float x) {
    float fhi = __uint_as_float(__float_as_uint(x) & 0xFFFF0000u);
    return (short)(__float_as_uint(x - fhi) >> 16);
}

__device__ __forceinline__ void split4(const float4 v, s16x4& hi, s16x4& lo) {
    hi[0] = bfhi(v.x); lo[0] = bflo(v.x);
    hi[1] = bfhi(v.y); lo[1] = bflo(v.y);
    hi[2] = bfhi(v.z); lo[2] = bflo(v.z);
    hi[3] = bfhi(v.w); lo[3] = bflo(v.w);
}

// ---------------------------------------------------------------------------
// Kernel 1: tA[b, c*H+o] = tanh( sum_h hidden[b,h]*attn_w[c,o,h] + attn_b[c,o] )
// GEMM M=256, N=16384, K=1024.  BM=256 (FULL M) x BN=32, grid 512, 256 thr
// (4 waves of 64(m)x32(n) via 2x 32x32x16 MFMA).
// A-operand: NO LDS — loaded as prepacked MFMA fragments (bf16 hi/lo planes in
// fragment order, built by gemm2's prepass) with coalesced 16B/lane global
// loads from the L2-resident 1MB hidP buffer.  Removing A from LDS cuts LDS
// traffic ~3.5x (round-3 was at the LDS BW wall: 120KB/CU-iter ~ 1400cy vs
// observed 1106cy iter-slot).  B: 32x32 fp32 slab, double-buffered LDS (10KB),
// ONE lgkmcnt-only barrier per slab; B prefetched 2 slabs ahead, A 1 ahead;
// no vmcnt(0) drains anywhere in the loop.
// ---------------------------------------------------------------------------
__global__ __launch_bounds__(256, 2) void gemm1_kernel(
    const short* __restrict__ hidH, const short* __restrict__ hidL,
    const float* __restrict__ attn_w, const float* __restrict__ attn_b,
    float* __restrict__ hp)
{
    __shared__ short BsH[2][32 * RS_];
    __shared__ short BsL[2][32 * RS_];

    const int tid  = threadIdx.x;
    const int wave = tid >> 6, lane = tid & 63;
    const int n0  = blockIdx.x * 32;
    const int l31 = lane & 31;
    const int kh  = (lane >> 5) * 8;     // k-half offset (shorts)

    f32x16 acc0, acc1;
    #pragma unroll
    for (int i = 0; i < 16; ++i) { acc0[i] = 0.f; acc1[i] = 0.f; }

    // B staging: 32 rows x 32 k fp32 = 256 float4 chunks, 1/thread.
    const int rB = tid >> 3, cB = (tid & 7) * 4;
    const float* pB = attn_w + (size_t)(n0 + rB) * HD_ + cB;
    const int wB = rB * RS_ + cB;
    const int boff = l31 * RS_ + kh;

    // A fragment bases (prepacked hidP layout: [s][k0][ks][lane][8] shorts,
    // strip s = 32 m-rows; this wave owns strips 2w, 2w+1 = rows w*64..+63).
    const size_t aBase = (size_t)(wave * 2) * 32768 + (size_t)lane * 8;
    const short* pH0 = hidH + aBase;
    const short* pH1 = hidH + aBase + 32768;
    const short* pL0 = hidL + aBase;
    const short* pL1 = hidL + aBase + 32768;

    float4 rb[2];                        // B prefetch regs (parity-indexed)
    short8 aH0[2][2], aH1[2][2], aL0[2][2], aL1[2][2];   // [set][ks], all
                                         // indices compile-time (rule #20)

    // prologue: B slab0 -> LDS buf0; B slab1 -> rb[1]; A slab0 -> set0
    rb[0] = *(const float4*)(pB);
    {   s16x4 h_, l_; split4(rb[0], h_, l_);
        *(s16x4*)(&BsH[0][wB]) = h_;
        *(s16x4*)(&BsL[0][wB]) = l_; }
    rb[1] = *(const float4*)(pB + 32);
    aH0[0][0] = *(const short8*)(pH0);
    aH0[0][1] = *(const short8*)(pH0 + 512);
    aH1[0][0] = *(const short8*)(pH1);
    aH1[0][1] = *(const short8*)(pH1 + 512);
    aL0[0][0] = *(const short8*)(pL0);
    aL0[0][1] = *(const short8*)(pL0 + 512);
    aL1[0][0] = *(const short8*)(pL1);
    aL1[0][1] = *(const short8*)(pL1 + 512);
    asm volatile("s_waitcnt lgkmcnt(0)" ::: "memory");
    __builtin_amdgcn_s_barrier();

    // Iter K0 (parity P): write B slab K0+1 (rb[P^1]) into buf P^1; load
    // rb[P] <- slab K0+2; load A set P^1 <- slab K0+1; compute buf P with
    // A set P; single lgkmcnt(0)+barrier.  Compiler-inserted vmcnt waits are
    // counted (never drain loads issued later in program order).
#define BODY(P, K0, DOW, DOLB, DOLA, DOB)                                     \
    {                                                                         \
        if (DOW) {                                                            \
            s16x4 h_, l_;                                                     \
            split4(rb[P ^ 1], h_, l_);                                        \
            *(s16x4*)(&BsH[P ^ 1][wB]) = h_;                                  \
            *(s16x4*)(&BsL[P ^ 1][wB]) = l_;                                  \
        }                                                                     \
        if (DOLB) rb[P] = *(const float4*)(pB + ((K0) + 2) * 32);             \
        if (DOLA) {                                                           \
            aH0[P ^ 1][0] = *(const short8*)(pH0 + ((K0) + 1) * 1024);        \
            aH0[P ^ 1][1] = *(const short8*)(pH0 + ((K0) + 1) * 1024 + 512);  \
            aH1[P ^ 1][0] = *(const short8*)(pH1 + ((K0) + 1) * 1024);        \
            aH1[P ^ 1][1] = *(const short8*)(pH1 + ((K0) + 1) * 1024 + 512);  \
            aL0[P ^ 1][0] = *(const short8*)(pL0 + ((K0) + 1) * 1024);        \
            aL0[P ^ 1][1] = *(const short8*)(pL0 + ((K0) + 1) * 1024 + 512);  \
            aL1[P ^ 1][0] = *(const short8*)(pL1 + ((K0) + 1) * 1024);        \
            aL1[P ^ 1][1] = *(const short8*)(pL1 + ((K0) + 1) * 1024 + 512);  \
        }                                                                     \
        {                                                                     \
            short8 bh0 = *(const short8*)(&BsH[P][boff]);                     \
            short8 bl0 = *(const short8*)(&BsL[P][boff]);                     \
            short8 bh1 = *(const short8*)(&BsH[P][boff + 16]);                \
            short8 bl1 = *(const short8*)(&BsL[P][boff + 16]);                \
            __builtin_amdgcn_s_setprio(1);                                    \
            acc0 = MFMA32(aH0[P][0], bh0, acc0);                              \
            acc1 = MFMA32(aH1[P][0], bh0, acc1);                              \
            acc0 = MFMA32(aL0[P][0], bh0, acc0);                              \
            acc1 = MFMA32(aL1[P][0], bh0, acc1);                              \
            acc0 = MFMA32(aH0[P][0], bl0, acc0);                              \
            acc1 = MFMA32(aH1[P][0], bl0, acc1);                              \
            acc0 = MFMA32(aH0[P][1], bh1, acc0);                              \
            acc1 = MFMA32(aH1[P][1], bh1, acc1);                              \
            acc0 = MFMA32(aL0[P][1], bh1, acc0);                              \
            acc1 = MFMA32(aL1[P][1], bh1, acc1);                              \
            acc0 = MFMA32(aH0[P][1], bl1, acc0);                              \
            acc1 = MFMA32(aH1[P][1], bl1, acc1);                              \
            __builtin_amdgcn_s_setprio(0);                                    \
        }                                                                     \
        if (DOB) {                                                            \
            asm volatile("s_waitcnt lgkmcnt(0)" ::: "memory");                \
            __builtin_amdgcn_s_barrier();                                     \
        }                                                                     \
    }

    for (int k0 = 0; k0 < 30; k0 += 2) {
        BODY(0, k0, 1, 1, 1, 1)
        BODY(1, k0 + 1, 1, 1, 1, 1)
    }
    BODY(0, 30, 1, 0, 1, 1)   // write slab31, load A slab31
    BODY(1, 31, 0, 0, 0, 0)   // compute only
#undef BODY

    // 32x32 C/D layout: col = lane&31, row = (r&3) + 8*(r>>2) + 4*(lane>>5).
    const int col  = n0 + l31;
    const float bias = attn_b[col];
    const int rbase = wave * 64 + (lane >> 5) * 4;
    float* dcol = hp + col;
    #pragma unroll
    for (int r = 0; r < 16; ++r) {
        const int row = rbase + (r & 3) + 8 * (r >> 2);
        dcol[(size_t)row * N1_]        = tanh_c(acc0[r] + bias);
        dcol[(size_t)(row + 32) * N1_] = tanh_c(acc1[r] + bias);
    }
}

// ---------------------------------------------------------------------------
// Kernel 2: tB[c,g,o] = tanh( sum_d enc[c,g,d] * attn_w[c,o,H+d] )
// Per-c GEMM M=32, N=1024, K=256; grid (16,16)=256 blocks.
// Prepass folded in: pack hidden (B,H) into bf16 hi/lo planes in MFMA-
// FRAGMENT order for gemm1's register-direct A loads:
//   hidP[s][k0][ks][lane][j] = hid[s*32+(lane&31)][k0*32+ks*16+(lane>>5)*8+j]
// (s=m-strip of 32 rows, k0=K-slab of 32, ks=k-half, j=0..7).
// ---------------------------------------------------------------------------
__global__ __launch_bounds__(256) void gemm2_kernel(
    const float* __restrict__ enc, const float* __restrict__ attn_w,
    const float* __restrict__ hidden, float* __restrict__ ep,
    short* __restrict__ hidH, short* __restrict__ hidL)
{
    const int tid  = threadIdx.x;
    const int wave = tid >> 6, lane = tid & 63;

    {   // fragment-pack prepass: 32768 lane-tasks over the first 128 blocks
        const int bid = blockIdx.y * 16 + blockIdx.x;
        const int gid = bid * 256 + tid;
        if (gid < 32768) {
            const int s   = gid >> 12;
            const int k0  = (gid >> 7) & 31;
            const int ks  = (gid >> 6) & 1;
            const int ln  = gid & 63;
            const int row = s * 32 + (ln & 31);
            const int colk = k0 * 32 + ks * 16 + (ln >> 5) * 8;
            const float* src = hidden + (size_t)row * H_ + colk;
            s16x4 h0, l0, h1, l1;
            split4(*(const float4*)src, h0, l0);
            split4(*(const float4*)(src + 4), h1, l1);
            *(short8*)(hidH + (size_t)gid * 8) =
                short8{h0[0],h0[1],h0[2],h0[3],h1[0],h1[1],h1[2],h1[3]};
            *(short8*)(hidL + (size_t)gid * 8) =
                short8{l0[0],l0[1],l0[2],l0[3],l1[0],l1[1],l1[2],l1[3]};
        }
    }

    const int c  = blockIdx.y;
    const int n0 = blockIdx.x * 64 + wave * 16;   // o tile, 16 per wave
    const int l16 = lane & 15;
    const int lk  = (lane >> 4) * 8;

#define MFMA16(a, b, c) __builtin_amdgcn_mfma_f32_16x16x32_bf16((a), (b), (c), 0, 0, 0)
    f32x4 acc[2];
    acc[0] = f32x4{0.f, 0.f, 0.f, 0.f};
    acc[1] = f32x4{0.f, 0.f, 0.f, 0.f};

    const float* encp = enc + c * (G_ * D_);
    const float* wp   = attn_w + (size_t)c * H_ * HD_ + H_;

    #pragma unroll
    for (int kk = 0; kk < 8; ++kk) {
        const int k0 = kk * 32 + lk;
        short8 ah[2], al[2], bh, bl;
        #pragma unroll
        for (int mi = 0; mi < 2; ++mi) {
            const float* p = encp + (mi * 16 + l16) * D_ + k0;
            s16x4 h0, l0, h1, l1;
            split4(*(const float4*)p, h0, l0);
            split4(*(const float4*)(p + 4), h1, l1);
            ah[mi] = short8{h0[0],h0[1],h0[2],h0[3],h1[0],h1[1],h1[2],h1[3]};
            al[mi] = short8{l0[0],l0[1],l0[2],l0[3],l1[0],l1[1],l1[2],l1[3]};
        }
        {
            const float* p = wp + (size_t)(n0 + l16) * HD_ + k0;
            s16x4 h0, l0, h1, l1;
            split4(*(const float4*)p, h0, l0);
            split4(*(const float4*)(p + 4), h1, l1);
            bh = short8{h0[0],h0[1],h0[2],h0[3],h1[0],h1[1],h1[2],h1[3]};
            bl = short8{l0[0],l0[1],l0[2],l0[3],l1[0],l1[1],l1[2],l1[3]};
        }
        #pragma unroll
        for (int mi = 0; mi < 2; ++mi) {
            acc[mi] = MFMA16(ah[mi], bh, acc[mi]);
            acc[mi] = MFMA16(al[mi], bh, acc[mi]);
            acc[mi] = MFMA16(ah[mi], bl, acc[mi]);
        }
    }

    const int lr = (lane >> 4) * 4;
    #pragma unroll
    for (int mi = 0; mi < 2; ++mi) {
        const int g = mi * 16 + lr;
        const int o = n0 + l16;
        float* dst = ep + (c * G_ + g) * H_ + o;
        f32x4 vacc = acc[mi];
        dst[0]      = tanh_c(vacc[0]);
        dst[H_]     = tanh_c(vacc[1]);
        dst[2 * H_] = tanh_c(vacc[2]);
        dst[3 * H_] = tanh_c(vacc[3]);
    }
#undef MFMA16
}

// ---------------------------------------------------------------------------
// Kernel 3: per (c, 4 b's): scores[g] = sum_h blend(tA,tB)*v where
// blend = (tA+tB)/(1+tA*tB) = tanh(A+B) exactly; softmax over g; att_cat out;
// weighted[b,c,d] = sum_g att*enc.
// ---------------------------------------------------------------------------
__global__ __launch_bounds__(256) void attn_kernel(
    const float* __restrict__ hp, const float* __restrict__ ep,
    const float* __restrict__ v, const float* __restrict__ enc,
    float* __restrict__ out, float* __restrict__ wt)
{
    const int c  = blockIdx.x;
    const int b0 = blockIdx.y * 4;
    const int tid  = threadIdx.x;
    const int wave = tid >> 6, lane = tid & 63;

    __shared__ float s_att[4][G_];
    __shared__ float s_sc[4][G_];

    // h index mapping: h = lane*4 + j*256 + e  (same partition for hp/ep/v)
    f32x4 vv[4], tav[4][4];
    const float* vrow = v + c * H_;
    #pragma unroll
    for (int j = 0; j < 4; ++j)
        vv[j] = *(const f32x4*)(vrow + lane * 4 + j * 256);
    #pragma unroll
    for (int bi = 0; bi < 4; ++bi) {
        const float* hprow = hp + (size_t)(b0 + bi) * N1_ + c * H_;
        #pragma unroll
        for (int j = 0; j < 4; ++j)
            tav[bi][j] = *(const f32x4*)(hprow + lane * 4 + j * 256);
    }

    #pragma unroll
    for (int gg = 0; gg < 8; ++gg) {
        const int g = wave * 8 + gg;
        const float* eprow = ep + (size_t)(c * G_ + g) * H_;
        float s[4] = {0.f, 0.f, 0.f, 0.f};
        #pragma unroll
        for (int j = 0; j < 4; ++j) {
            const f32x4 tb = *(const f32x4*)(eprow + lane * 4 + j * 256);
            #pragma unroll
            for (int e = 0; e < 4; ++e) {
                const float tbx = tb[e];
                const float w   = vv[j][e];
                #pragma unroll
                for (int bi = 0; bi < 4; ++bi) {
                    const float ta  = tav[bi][j][e];
                    const float num = ta + tbx;
                    const float den = fmaf(ta, tbx, 1.f);
                    s[bi] = fmaf(num * __builtin_amdgcn_rcpf(den), w, s[bi]);
                }
            }
        }
        #pragma unroll
        for (int off = 32; off > 0; off >>= 1) {
            s[0] += __shfl_down(s[0], off, 64);
            s[1] += __shfl_down(s[1], off, 64);
            s[2] += __shfl_down(s[2], off, 64);
            s[3] += __shfl_down(s[3], off, 64);
        }
        if (lane == 0) {
            s_sc[0][g] = s[0]; s_sc[1][g] = s[1];
            s_sc[2][g] = s[2]; s_sc[3][g] = s[3];
        }
    }
    __syncthreads();

    if (tid < 128) {
        const int bi = tid >> 5, g = tid & 31;
        float sv = s_sc[bi][g];
        float m = sv;
        #pragma unroll
        for (int off = 16; off > 0; off >>= 1)
            m = fmaxf(m, __shfl_xor(m, off, 32));
        const float e = __expf(sv - m);
        float sum = e;
        #pragma unroll
        for (int off = 16; off > 0; off >>= 1)
            sum += __shfl_xor(sum, off, 32);
        const float a = e / sum;
        s_att[bi][g] = a;
        out[(size_t)(b0 + bi) * (C_ * G_) + c * G_ + g] = a;   // att_cat
    }
    __syncthreads();

    // weighted[b,c,d], thread = d; enc element shared across the 4 b's
    float w0 = 0.f, w1 = 0.f, w2 = 0.f, w3 = 0.f;
    const float* encc = enc + c * (G_ * D_) + tid;
    #pragma unroll
    for (int g = 0; g < G_; ++g) {
        const float e = encc[g * D_];
        w0 = fmaf(s_att[0][g], e, w0);
        w1 = fmaf(s_att[1][g], e, w1);
        w2 = fmaf(s_att[2][g], e, w2);
        w3 = fmaf(s_att[3][g], e, w3);
    }
    wt[(size_t)((b0 + 0) * C_ + c) * D_ + tid] = w0;
    wt[(size_t)((b0 + 1) * C_ + c) * D_ + tid] = w1;
    wt[(size_t)((b0 + 2) * C_ + c) * D_ + tid] = w2;
    wt[(size_t)((b0 + 3) * C_ + c) * D_ + tid] = w3;
}

// ---------------------------------------------------------------------------
// Kernel 4: pooled[b,d] = mean_c weighted; out[b,o] = pooled.out_w[o,:] + out_b
// ---------------------------------------------------------------------------
__global__ __launch_bounds__(256) void out_kernel(
    const float* __restrict__ wt, const float* __restrict__ out_w,
    const float* __restrict__ out_b, float* __restrict__ out)
{
    const int b = blockIdx.x, tid = threadIdx.x;
    __shared__ float pooled[D_];

    float s = 0.f;
    #pragma unroll
    for (int c = 0; c < C_; ++c)
        s += wt[(size_t)(b * C_ + c) * D_ + tid];
    pooled[tid] = s * (1.f / 16.f);
    __syncthreads();

    float acc = out_b[tid];
    const float* wrow = out_w + tid * D_;
    #pragma unroll 8
    for (int dc = 0; dc < 64; ++dc) {
        float4 w4 = *(const float4*)(wrow + dc * 4);
        acc += pooled[dc * 4 + 0] * w4.x;
        acc += pooled[dc * 4 + 1] * w4.y;
        acc += pooled[dc * 4 + 2] * w4.z;
        acc += pooled[dc * 4 + 3] * w4.w;
    }
    out[(size_t)B_ * (C_ * G_) + b * O_ + tid] = acc;
}

extern "C" void kernel_launch(void* const* d_in, const int* in_sizes, int n_in,
                              void* d_out, int out_size, void* d_ws, size_t ws_size,
                              hipStream_t stream) {
    const float* hidden = (const float*)d_in[0];   // (B,H)     fp32
    const float* enc    = (const float*)d_in[1];   // (C,G,D)   fp32
    const float* attn_w = (const float*)d_in[2];   // (C,H,H+D) fp32
    const float* attn_b = (const float*)d_in[3];   // (C,H)     fp32
    const float* v      = (const float*)d_in[4];   // (C,H)     fp32
    const float* out_w  = (const float*)d_in[5];   // (O,D)     fp32
    const float* out_b  = (const float*)d_in[6];   // (O,)      fp32
    float* out = (float*)d_out;                    // att_cat (B,C*G) ++ out (B,O)

    float* hp = (float*)d_ws;                      // (B, C*H)  tA fp32: 16.78 MB
    float* ep = hp + (size_t)B_ * N1_;             // (C, G, H) tB fp32:  2.10 MB
    float* wt = ep + (size_t)C_ * G_ * H_;         // (B, C, D) fp32:     4.19 MB
    short* hidH = (short*)(wt + (size_t)B_ * C_ * D_);  // (B,H) bf16 hi frag-packed: 512 KB
    short* hidL = hidH + (size_t)B_ * H_;               // (B,H) bf16 lo frag-packed: 512 KB

    // gemm2 first: it also produces the fragment-packed hidden planes gemm1 reads.
    gemm2_kernel<<<dim3(16, C_), 256, 0, stream>>>(enc, attn_w, hidden, ep, hidH, hidL);
    gemm1_kernel<<<512, 256, 0, stream>>>(hidH, hidL, attn_w, attn_b, hp);
    attn_kernel<<<dim3(C_, B_ / 4), 256, 0, stream>>>(hp, ep, v, enc, out, wt);
    out_kernel<<<B_, 256, 0, stream>>>(wt, out_w, out_b, out);
}